// Round 10
// baseline (1154.970 us; speedup 1.0000x reference)
//
#include <hip/hip_runtime.h>
#include <hip/hip_bf16.h>

typedef unsigned short u16;
typedef unsigned short u16x8 __attribute__((ext_vector_type(8)));
typedef __bf16 bf16x8 __attribute__((ext_vector_type(8)));
typedef float f32x4 __attribute__((ext_vector_type(4)));

#define LRS 0.2f

__device__ __forceinline__ u16 f2b(float f) {
  __hip_bfloat16 h = __float2bfloat16(f);
  return __builtin_bit_cast(u16, h);
}

// ---------------------------------------------------------------------------
// R rows (LDS f32, stride K) x W[O][K] f32 -> y[R][O]; KSEG lanes per K.
// ---------------------------------------------------------------------------
template<int K, int O, int KSEG, int R>
__device__ __forceinline__ void gemm_rowsR(const float* xr, const float* W, const float* bias,
                                           float* yl, float* yg, int ygstride) {
  constexpr int KPT = K / KSEG;
  constexpr int OPP = 256 / KSEG;
  const int t = threadIdx.x;
  const int ks = t % KSEG;
  const int oi = t / KSEG;
#pragma unroll
  for (int pass = 0; pass < O / OPP; ++pass) {
    const int o = pass * OPP + oi;
    float a[R];
#pragma unroll
    for (int r = 0; r < R; ++r) a[r] = 0.0f;
    const float* wp = W + (size_t)o * K + ks * KPT;
    const float* xb = xr + ks * KPT;
#pragma unroll 4
    for (int kc = 0; kc < KPT; kc += 4) {
      f32x4 w4 = *(const f32x4*)(wp + kc);
#pragma unroll
      for (int r = 0; r < R; ++r) {
        f32x4 x = *(const f32x4*)(xb + r * K + kc);
#pragma unroll
        for (int j = 0; j < 4; ++j) a[r] += x[j] * w4[j];
      }
    }
#pragma unroll
    for (int d = 1; d < KSEG; d <<= 1)
#pragma unroll
      for (int r = 0; r < R; ++r) a[r] += __shfl_xor(a[r], d, 64);
    if (ks == 0) {
      float bv = bias ? bias[o] : 0.0f;
#pragma unroll
      for (int r = 0; r < R; ++r) {
        float v = a[r] + bv;
        if (yl) yl[r * O + o] = v;
        if (yg) yg[(size_t)r * ygstride + o] = v;
      }
    }
  }
}

// ---------------------------------------------------------------------------
// W1: fold weights. Mfull[hf][c]; vf[c][8] f32 (score vectors); cbe; sconst.
// ---------------------------------------------------------------------------
__global__ __launch_bounds__(256) void kW1(const float* We_w, const float* We_b, const float* attn,
                                           const float* We2_w, const float* We2_b,
                                           const float* edge_w, const float* edge_b,
                                           float* Mfull, float* vf, float* cbe, float* sconst) {
  int gid = blockIdx.x * 256 + threadIdx.x;
  if (gid < 16384) {
    int hf = gid >> 7, c = gid & 127;
    int h = hf >> 4, fo = hf & 15;
    float s = 0;
    for (int e = 0; e < 16; ++e)
      s += edge_w[fo * 176 + e] * We2_w[(h * 16 + e) * 128 + c];
    Mfull[hf * 128 + c] = s;
  } else if (gid < 16384 + 1024) {
    int idx = gid - 16384;
    int c = idx >> 3, h = idx & 7;
    float s = 0;
    for (int e = 0; e < 16; ++e)
      s += We_w[(h * 16 + e) * 128 + c] * attn[128 + e];
    vf[c * 8 + h] = s;
  } else if (gid < 17408 + 128) {
    int hf = gid - 17408;
    int h = hf >> 4, fo = hf & 15;
    float s = edge_b[fo];
    for (int e = 0; e < 16; ++e)
      s += We2_b[h * 16 + e] * edge_w[fo * 176 + e];
    cbe[hf] = s;
  } else if (gid < 17536 + 8) {
    int h = gid - 17536;
    float s = 0;
    for (int e = 0; e < 16; ++e)
      s += We_b[h * 16 + e] * attn[128 + e];
    sconst[h] = s;
  }
}

// W2: G[o][c] bf16
__global__ __launch_bounds__(256) void kW2(const float* oute_w, const float* Mfull, u16* Gb) {
  int gid = blockIdx.x * 256 + threadIdx.x;
  int o = gid >> 7, c = gid & 127;
  float s = 0;
  for (int k = 0; k < 128; ++k)
    s += oute_w[o * 128 + k] * Mfull[k * 128 + c];
  Gb[o * 128 + c] = f2b(s);
}

// ---------------------------------------------------------------------------
// N1: per 2 node-rows (grid 512): npj, dpj, node_wh, srow, scol
// ---------------------------------------------------------------------------
__global__ __launch_bounds__(256) void kN1(const float* node, const float* diff,
                                           const float* Wn_w, const float* Wn_b,
                                           const float* Wd_w, const float* Wd_b,
                                           const float* Wh_w, const float* Wh_b,
                                           const float* attn, const float* sconst,
                                           float* npj_g, float* nwh_g,
                                           float* srow_g, float* scol_g) {
  __shared__ float nrow[2 * 512], npjl[2 * 512], drow[2 * 128], dpjl[2 * 128];
  const int t = threadIdx.x;
  const int r0 = blockIdx.x * 2;
  *(f32x4*)&nrow[t * 4] = *(const f32x4*)(node + (size_t)r0 * 512 + t * 4);
  if (t < 64) *(f32x4*)&drow[t * 4] = *(const f32x4*)(diff + (size_t)r0 * 128 + t * 4);
  __syncthreads();
  gemm_rowsR<512, 512, 4, 2>(nrow, Wn_w, Wn_b, npjl, npj_g + (size_t)r0 * 512, 512);
  gemm_rowsR<128, 128, 4, 2>(drow, Wd_w, Wd_b, dpjl, nullptr, 0);
  __syncthreads();
  {
    int d = t & 63, hh = t >> 6;
#pragma unroll
    for (int hi = 0; hi < 2; ++hi) {
      int h = hh + hi * 4;
      float wb = Wh_b[d];
      float acc[2] = {wb, wb};
      for (int k = 0; k < 64; ++k) {
        float w = Wh_w[d * 64 + k];
#pragma unroll
        for (int r = 0; r < 2; ++r) acc[r] += npjl[r * 512 + h * 64 + k] * w;
      }
#pragma unroll
      for (int r = 0; r < 2; ++r) nwh_g[(size_t)(r0 + r) * 512 + h * 64 + d] = acc[r];
    }
  }
  if (t < 16) {
    int r = t >> 3, h = t & 7;
    float shi = 0, shj = 0, sdi = 0, sdj = 0;
    for (int d = 0; d < 64; ++d) {
      float x = npjl[r * 512 + h * 64 + d];
      shi += x * attn[d];
      shj += x * attn[64 + d];
    }
    for (int e = 0; e < 16; ++e) {
      float x = dpjl[r * 128 + h * 16 + e];
      sdi += x * attn[144 + e];
      sdj += x * attn[160 + e];
    }
    srow_g[(r0 + r) * 8 + h] = shi + sdi + sconst[h];
    scol_g[(r0 + r) * 8 + h] = shj + sdj;
  }
}

// ---------------------------------------------------------------------------
// S: streaming scores + bf16 cache. One edge row per thread, grid 2048.
// Deep-MLP: two 8-deep f32x4 load batches with lookahead; no barriers in the
// stream; vf broadcast from LDS. se[row][8] f32; abf[row][128] bf16 linear.
// ---------------------------------------------------------------------------
__global__ __launch_bounds__(256) void kS(const float* __restrict__ edge,
                                          const float* __restrict__ vf,
                                          float* __restrict__ se, u16* __restrict__ abf) {
  __shared__ float vl[1024];
  const int t = threadIdx.x;
  *(f32x4*)&vl[t * 4] = *(const f32x4*)(vf + t * 4);
  __syncthreads();
  const size_t row = (size_t)blockIdx.x * 256 + t;
  const float* rp = edge + row * 128;
  u16* cp = abf ? abf + row * 128 : nullptr;
  f32x4 A[8], B[8];
#pragma unroll
  for (int q = 0; q < 8; ++q) A[q] = *(const f32x4*)(rp + q * 4);
#pragma unroll
  for (int q = 0; q < 8; ++q) B[q] = *(const f32x4*)(rp + 32 + q * 4);
  f32x4 acc0 = {0, 0, 0, 0}, acc1 = {0, 0, 0, 0};

#define PROCG(BUF, CB)                                                     \
  {                                                                        \
    _Pragma("unroll") for (int q = 0; q < 8; ++q) {                        \
      f32x4 v = BUF[q];                                                    \
      int c = CB + q * 4;                                                  \
      _Pragma("unroll") for (int j = 0; j < 4; ++j) {                      \
        f32x4 w0 = *(const f32x4*)&vl[(c + j) * 8];                        \
        f32x4 w1 = *(const f32x4*)&vl[(c + j) * 8 + 4];                    \
        acc0 += v[j] * w0;                                                 \
        acc1 += v[j] * w1;                                                 \
      }                                                                    \
    }                                                                      \
    if (cp) {                                                              \
      _Pragma("unroll") for (int q = 0; q < 8; q += 2) {                   \
        u16x8 pk;                                                          \
        _Pragma("unroll") for (int j = 0; j < 4; ++j) {                    \
          pk[j] = f2b(BUF[q][j]);                                          \
          pk[4 + j] = f2b(BUF[q + 1][j]);                                  \
        }                                                                  \
        *(u16x8*)(cp + CB + q * 4) = pk;                                   \
      }                                                                    \
    }                                                                      \
  }

  PROCG(A, 0);
#pragma unroll
  for (int q = 0; q < 8; ++q) A[q] = *(const f32x4*)(rp + 64 + q * 4);
  PROCG(B, 32);
#pragma unroll
  for (int q = 0; q < 8; ++q) B[q] = *(const f32x4*)(rp + 96 + q * 4);
  PROCG(A, 64);
  PROCG(B, 96);
#undef PROCG
  *(f32x4*)(se + row * 8)     = acc0;
  *(f32x4*)(se + row * 8 + 4) = acc1;
}

// ---------------------------------------------------------------------------
// SM: per (b,l): read se, softmax (bias+lrelu+diag), write P bf16 + invs.
// ---------------------------------------------------------------------------
__global__ __launch_bounds__(256) void kSM(const float* se, const float* srow, const float* scol,
                                           u16* P, float* invs) {
  __shared__ float smx[512 * 9];
  __shared__ float red[256];
  __shared__ float mxh8[8];
  const int bl = blockIdx.x;
  const int b = bl >> 9, l = bl & 511;
  const int t = threadIdx.x;
  const int h = t & 7, seg = t >> 3;
  const float* sb = se + (size_t)bl * 4096;
#pragma unroll
  for (int k = 0; k < 4; ++k) {
    int idx = k * 1024 + t * 4;
    int m = idx >> 3, hh = idx & 7;
    f32x4 v = *(const f32x4*)(sb + idx);
#pragma unroll
    for (int j = 0; j < 4; ++j) smx[m * 9 + hh + j] = v[j];
  }
  __syncthreads();
  const float srh2 = srow[(size_t)bl * 8 + h];
  float mx = -__builtin_inff();
#pragma unroll 4
  for (int i = 0; i < 16; ++i) {
    int m = seg * 16 + i;
    float sv = smx[m * 9 + h] + srh2 + scol[((size_t)b * 512 + m) * 8 + h];
    sv = (m == l) ? -__builtin_inff() : (sv >= 0.0f ? sv : LRS * sv);
    smx[m * 9 + h] = sv;
    mx = fmaxf(mx, sv);
  }
  red[t] = mx;
  __syncthreads();
  if (t < 8) {
    float m2 = -__builtin_inff();
    for (int sg = 0; sg < 32; ++sg) m2 = fmaxf(m2, red[sg * 8 + t]);
    mxh8[t] = m2;
  }
  __syncthreads();
  float mh = mxh8[h];
  float smv = 0;
#pragma unroll 4
  for (int i = 0; i < 16; ++i) {
    int m = seg * 16 + i;
    float p = __expf(smx[m * 9 + h] - mh);
    smx[m * 9 + h] = p;
    smv += p;
  }
  red[t] = smv;
  __syncthreads();
  if (t < 8) {
    float s2 = 0;
    for (int sg = 0; sg < 32; ++sg) s2 += red[sg * 8 + t];
    invs[(size_t)bl * 8 + t] = 1.0f / s2;
  }
  __syncthreads();
#pragma unroll
  for (int k = 0; k < 2; ++k) {
    int c = k * 256 + t;
    int hp = c >> 6, mb = (c & 63) * 8;
    u16x8 pk;
#pragma unroll
    for (int j = 0; j < 8; ++j) pk[j] = f2b(smx[(mb + j) * 9 + hp]);
    *(u16x8*)(P + (((size_t)b * 8 + hp) * 512 + l) * 512 + mb) = pk;
  }
}

// ---------------------------------------------------------------------------
// Agg: per (b,h,ltile64): agg[l][d] = sum_m P[b,h,l,m]*nwh[b,m,h*64+d]
// ---------------------------------------------------------------------------
__global__ __launch_bounds__(256) void kAgg(const u16* P, const float* nwh, const float* npj,
                                            const float* invs, float* nnp) {
  __shared__ u16 Pt[8192];
  __shared__ u16 Vt[8192];
  const int bid = blockIdx.x;
  const int lt = bid & 7, h = (bid >> 3) & 7, b = bid >> 6;
  const int l0 = lt * 64;
  const int t = threadIdx.x;
  const int lane = t & 63, w = t >> 6;
  const int colL = lane & 15, kg = lane >> 4;

  f32x4 acc[4] = {};
  for (int mc = 0; mc < 4; ++mc) {
#pragma unroll
    for (int q = 0; q < 4; ++q) {
      int c = q * 256 + t;
      int row = c >> 4, cu = c & 15;
      u16x8 a8 = *(const u16x8*)(P + (((size_t)b * 8 + h) * 512 + l0 + row) * 512 + mc * 128 + cu * 8);
      *(u16x8*)(Pt + (row * 16 + (cu ^ (row & 7))) * 8) = a8;
    }
#pragma unroll
    for (int q = 0; q < 8; ++q) {
      int c = q * 256 + t;
      int m = c >> 4, d4 = (c & 15) * 4;
      f32x4 v = *(const f32x4*)(nwh + ((size_t)b * 512 + mc * 128 + m) * 512 + h * 64 + d4);
#pragma unroll
      for (int j = 0; j < 4; ++j) {
        int d = d4 + j;
        Vt[(d * 16 + ((m >> 3) ^ (d & 7))) * 8 + (m & 7)] = f2b(v[j]);
      }
    }
    __syncthreads();
#pragma unroll
    for (int kc = 0; kc < 4; ++kc) {
      int cu = kc * 4 + kg;
      int prow = w * 16 + colL;
      bf16x8 af = *(bf16x8*)(Pt + (prow * 16 + (cu ^ (prow & 7))) * 8);
#pragma unroll
      for (int n = 0; n < 4; ++n) {
        int d = n * 16 + colL;
        bf16x8 bf = *(bf16x8*)(Vt + (d * 16 + (cu ^ (d & 7))) * 8);
        acc[n] = __builtin_amdgcn_mfma_f32_16x16x32_bf16(af, bf, acc[n], 0, 0, 0);
      }
    }
    __syncthreads();
  }
#pragma unroll
  for (int r = 0; r < 4; ++r) {
    int l = l0 + w * 16 + kg * 4 + r;
    float iv = invs[((size_t)b * 512 + l) * 8 + h];
#pragma unroll
    for (int n = 0; n < 4; ++n) {
      int o = h * 64 + n * 16 + colL;
      size_t idx = ((size_t)b * 512 + l) * 512 + o;
      float a = acc[n][r] * iv;
      a = a >= 0.0f ? a : LRS * a;
      nnp[idx] = npj[idx] + a;
    }
  }
}

// ---------------------------------------------------------------------------
// N234 (fused, 2 rows/block, grid 512): nnp -> out0 -> np2/dp2 -> R -> Pl/Pm
// ---------------------------------------------------------------------------
__global__ __launch_bounds__(256) void kN234(const float* nnp, const float* diff,
                                             const float* outn_w, const float* outn_b,
                                             const float* Wn2_w, const float* Wn2_b,
                                             const float* Wd2_w, const float* Wd2_b,
                                             const float* edge_w, const float* cbe,
                                             const float* oute_w, const float* oute_b,
                                             float* out0, float* Pl, float* Pm) {
  __shared__ float xr[2 * 512], o0l[2 * 512], np2l[2 * 512], dr[2 * 128], dp2l[2 * 128];
  __shared__ float Rls[2 * 128], Rms[2 * 128];
  const int t = threadIdx.x;
  const int r0 = blockIdx.x * 2;
  *(f32x4*)&xr[t * 4] = *(const f32x4*)(nnp + (size_t)r0 * 512 + t * 4);
  if (t < 64) *(f32x4*)&dr[t * 4] = *(const f32x4*)(diff + (size_t)r0 * 128 + t * 4);
  __syncthreads();
  gemm_rowsR<512, 512, 4, 2>(xr, outn_w, outn_b, o0l, out0 + (size_t)r0 * 512, 512);
  gemm_rowsR<128, 128, 4, 2>(dr, Wd2_w, Wd2_b, dp2l, nullptr, 0);
  __syncthreads();
  gemm_rowsR<512, 512, 4, 2>(o0l, Wn2_w, Wn2_b, np2l, nullptr, 0);
  __syncthreads();
  {
    int hf = t & 127, which = t >> 7;
    int h = hf >> 4, fo = hf & 15;
    const float* wh = edge_w + fo * 176 + 16 + which * 64;
    const float* wd = edge_w + fo * 176 + 144 + which * 16;
    float add = which ? 0.0f : cbe[hf];
    float* dst = which ? Rms : Rls;
#pragma unroll
    for (int r = 0; r < 2; ++r) {
      float a = add;
      for (int d = 0; d < 64; ++d) a += np2l[r * 512 + h * 64 + d] * wh[d];
      for (int e = 0; e < 16; ++e) a += dp2l[r * 128 + h * 16 + e] * wd[e];
      dst[r * 128 + hf] = a;
    }
  }
  __syncthreads();
  gemm_rowsR<128, 128, 4, 2>(Rls, oute_w, oute_b, nullptr, Pl + (size_t)r0 * 128, 128);
  gemm_rowsR<128, 128, 4, 2>(Rms, oute_w, nullptr, nullptr, Pm + (size_t)r0 * 128, 128);
}

// ---------------------------------------------------------------------------
// Ec: grid 8192 (64-row tile). G in VGPRs, single 16KB At stage, one barrier.
// ---------------------------------------------------------------------------
__global__ __launch_bounds__(256) void kEc(const u16* Abf, const u16* Gb,
                                           const float* Pl, const float* Pm, float* oute) {
  __shared__ u16 At[8192];
  const int tile = blockIdx.x;
  const int bl = tile >> 3;
  const int b = bl >> 9;
  const int r0 = (tile & 7) * 64;
  const int t = threadIdx.x, lane = t & 63, w = t >> 6;
  const int colL = lane & 15, kg = lane >> 4;

  bf16x8 gf[2][4];
#pragma unroll
  for (int n = 0; n < 2; ++n)
#pragma unroll
    for (int ks = 0; ks < 4; ++ks) {
      int o = w * 32 + n * 16 + colL;
      gf[n][ks] = *(const bf16x8*)(Gb + o * 128 + ks * 32 + kg * 8);
    }
  f32x4 plv4[2];
#pragma unroll
  for (int n = 0; n < 2; ++n)
    plv4[n] = *(const f32x4*)(Pl + (size_t)bl * 128 + w * 32 + n * 16 + kg * 4);

  const u16* src = Abf + ((size_t)bl * 512 + r0) * 128;
#pragma unroll
  for (int q = 0; q < 4; ++q) {
    int c = q * 256 + t;
    int row = c >> 4, cu = c & 15;
    *(u16x8*)(At + (row * 16 + (cu ^ (row & 7))) * 8) = *(const u16x8*)(src + c * 8);
  }
  __syncthreads();

  f32x4 acc[4][2] = {};
#pragma unroll
  for (int i = 0; i < 4; ++i) {
#pragma unroll
    for (int ks = 0; ks < 4; ++ks) {
      int cu = ks * 4 + kg;
      int row = i * 16 + colL;
      bf16x8 af = *(bf16x8*)(At + (row * 16 + (cu ^ (row & 7))) * 8);
#pragma unroll
      for (int n = 0; n < 2; ++n)
        acc[i][n] = __builtin_amdgcn_mfma_f32_16x16x32_bf16(gf[n][ks], af, acc[i][n], 0, 0, 0);
    }
  }
  float* ob = oute + ((size_t)bl * 512 + r0) * 128;
#pragma unroll
  for (int i = 0; i < 4; ++i) {
    int m = i * 16 + colL;
    const float* pmp = Pm + ((size_t)b * 512 + r0 + m) * 128;
    float* orow = ob + (size_t)m * 128;
#pragma unroll
    for (int n = 0; n < 2; ++n) {
      int oc = w * 32 + n * 16 + kg * 4;
      f32x4 pm4 = *(const f32x4*)(pmp + oc);
      f32x4 o4;
#pragma unroll
      for (int r = 0; r < 4; ++r) o4[r] = acc[i][n][r] + plv4[n][r] + pm4[r];
      *(f32x4*)(orow + oc) = o4;
    }
  }
}

// ---------------------------------------------------------------------------
// Ed: fallback direct-f32 edge GEMM.
// ---------------------------------------------------------------------------
__global__ __launch_bounds__(256) void kEd(const float* edge, const u16* Gb,
                                           const float* Pl, const float* Pm, float* oute) {
  __shared__ u16 At[8192];
  const int tile = blockIdx.x;
  const int bl = tile >> 3;
  const int b = bl >> 9;
  const int r0 = (tile & 7) * 64;
  const int t = threadIdx.x, lane = t & 63, w = t >> 6;
  const int colL = lane & 15, kg = lane >> 4;
  bf16x8 gf[2][4];
#pragma unroll
  for (int n = 0; n < 2; ++n)
#pragma unroll
    for (int ks = 0; ks < 4; ++ks) {
      int o = w * 32 + n * 16 + colL;
      gf[n][ks] = *(const bf16x8*)(Gb + o * 128 + ks * 32 + kg * 8);
    }
  f32x4 plv4[2];
#pragma unroll
  for (int n = 0; n < 2; ++n)
    plv4[n] = *(const f32x4*)(Pl + (size_t)bl * 128 + w * 32 + n * 16 + kg * 4);

  const int arow = t >> 2, aseg = t & 3;
  {
    const float* p = edge + ((size_t)bl * 512 + r0 + arow) * 128 + aseg * 32;
    f32x4 v[8];
#pragma unroll
    for (int q = 0; q < 8; ++q) v[q] = *(const f32x4*)(p + q * 4);
#pragma unroll
    for (int jj = 0; jj < 4; ++jj) {
      u16x8 a8;
#pragma unroll
      for (int j2 = 0; j2 < 4; ++j2) {
        a8[j2]     = f2b(v[2 * jj][j2]);
        a8[4 + j2] = f2b(v[2 * jj + 1][j2]);
      }
      int cu = aseg * 4 + jj;
      *(u16x8*)(At + (arow * 16 + (cu ^ (arow & 7))) * 8) = a8;
    }
  }
  __syncthreads();
  f32x4 acc[4][2] = {};
#pragma unroll
  for (int i = 0; i < 4; ++i) {
#pragma unroll
    for (int ks = 0; ks < 4; ++ks) {
      int cu = ks * 4 + kg;
      int row = i * 16 + colL;
      bf16x8 af = *(bf16x8*)(At + (row * 16 + (cu ^ (row & 7))) * 8);
#pragma unroll
      for (int n = 0; n < 2; ++n)
        acc[i][n] = __builtin_amdgcn_mfma_f32_16x16x32_bf16(gf[n][ks], af, acc[i][n], 0, 0, 0);
    }
  }
  float* ob = oute + ((size_t)bl * 512 + r0) * 128;
#pragma unroll
  for (int i = 0; i < 4; ++i) {
    int m = i * 16 + colL;
    const float* pmp = Pm + ((size_t)b * 512 + r0 + m) * 128;
    float* orow = ob + (size_t)m * 128;
#pragma unroll
    for (int n = 0; n < 2; ++n) {
      int oc = w * 32 + n * 16 + kg * 4;
      f32x4 pm4 = *(const f32x4*)(pmp + oc);
      f32x4 o4;
#pragma unroll
      for (int r = 0; r < 4; ++r) o4[r] = acc[i][n][r] + plv4[n][r] + pm4[r];
      *(f32x4*)(orow + oc) = o4;
    }
  }
}

extern "C" void kernel_launch(void* const* d_in, const int* in_sizes, int n_in,
                              void* d_out, int out_size, void* d_ws, size_t ws_size,
                              hipStream_t stream) {
  (void)in_sizes; (void)n_in; (void)out_size;
  const float* node   = (const float*)d_in[0];
  const float* edge   = (const float*)d_in[1];
  const float* diff   = (const float*)d_in[2];
  const float* Wn_w   = (const float*)d_in[3];
  const float* Wn_b   = (const float*)d_in[4];
  const float* We_w   = (const float*)d_in[5];
  const float* We_b   = (const float*)d_in[6];
  const float* Wd_w   = (const float*)d_in[7];
  const float* Wd_b   = (const float*)d_in[8];
  const float* Wh_w   = (const float*)d_in[9];
  const float* Wh_b   = (const float*)d_in[10];
  const float* attn   = (const float*)d_in[11];
  const float* outn_w = (const float*)d_in[12];
  const float* outn_b = (const float*)d_in[13];
  const float* Wn2_w  = (const float*)d_in[14];
  const float* Wn2_b  = (const float*)d_in[15];
  const float* We2_w  = (const float*)d_in[16];
  const float* We2_b  = (const float*)d_in[17];
  const float* Wd2_w  = (const float*)d_in[18];
  const float* Wd2_b  = (const float*)d_in[19];
  const float* edge_w = (const float*)d_in[20];
  const float* edge_b = (const float*)d_in[21];
  const float* oute_w = (const float*)d_in[22];
  const float* oute_b = (const float*)d_in[23];

  float* out0 = (float*)d_out;
  float* out1 = out0 + 524288;

  float* f = (float*)d_ws;
  size_t off = 0;
  auto alloc = [&](size_t n) { float* p = f + off; off += (n + 7) & ~(size_t)7; return p; };
  float* npj    = alloc(524288);
  float* nwh    = alloc(524288);
  float* srow   = alloc(8192);
  float* scol   = alloc(8192);
  float* sconst = alloc(8);
  float* cbe    = alloc(128);
  float* Mfull  = alloc(16384);
  float* nnp    = alloc(524288);
  float* Pl     = alloc(131072);
  float* Pm     = alloc(131072);
  float* invs   = alloc(8192);
  float* vf     = alloc(1024);
  float* se     = alloc(4194304);          // 524288 rows x 8 f32
  u16* Gb = (u16*)(f + off); off += 8192;
  u16* P  = (u16*)(f + off); off += 2097152;
  const size_t abf_elems = (size_t)2 * 512 * 512 * 128;
  bool cache = ws_size >= off * 4 + abf_elems * 2 + 256;
  u16* Abf = cache ? (u16*)(f + off) : nullptr;

  hipLaunchKernelGGL(kW1, dim3(70), dim3(256), 0, stream,
                     We_w, We_b, attn, We2_w, We2_b, edge_w, edge_b, Mfull, vf, cbe, sconst);
  hipLaunchKernelGGL(kW2, dim3(64), dim3(256), 0, stream, oute_w, Mfull, Gb);
  hipLaunchKernelGGL(kN1, dim3(512), dim3(256), 0, stream,
                     node, diff, Wn_w, Wn_b, Wd_w, Wd_b, Wh_w, Wh_b, attn, sconst,
                     npj, nwh, srow, scol);
  hipLaunchKernelGGL(kS, dim3(2048), dim3(256), 0, stream, edge, vf, se, Abf);
  hipLaunchKernelGGL(kSM, dim3(1024), dim3(256), 0, stream, se, srow, scol, P, invs);
  hipLaunchKernelGGL(kAgg, dim3(128), dim3(256), 0, stream, P, nwh, npj, invs, nnp);
  hipLaunchKernelGGL(kN234, dim3(512), dim3(256), 0, stream,
                     nnp, diff, outn_w, outn_b, Wn2_w, Wn2_b, Wd2_w, Wd2_b,
                     edge_w, cbe, oute_w, oute_b, out0, Pl, Pm);
  if (cache)
    hipLaunchKernelGGL(kEc, dim3(8192), dim3(256), 0, stream, Abf, Gb, Pl, Pm, out1);
  else
    hipLaunchKernelGGL(kEd, dim3(8192), dim3(256), 0, stream, edge, Gb, Pl, Pm, out1);
}

// Round 11
// 465.912 us; speedup vs baseline: 2.4789x; 2.4789x over previous
//
#include <hip/hip_runtime.h>
#include <hip/hip_bf16.h>

typedef unsigned short u16;
typedef unsigned short u16x4 __attribute__((ext_vector_type(4)));
typedef unsigned short u16x8 __attribute__((ext_vector_type(8)));
typedef __bf16 bf16x8 __attribute__((ext_vector_type(8)));
typedef float f32x4 __attribute__((ext_vector_type(4)));

#define LRS 0.2f

__device__ __forceinline__ u16 f2b(float f) {
  __hip_bfloat16 h = __float2bfloat16(f);
  return __builtin_bit_cast(u16, h);
}

// ---------------------------------------------------------------------------
// R rows (LDS f32, stride K) x W[O][K] f32 -> y[R][O]; KSEG lanes per K.
// ---------------------------------------------------------------------------
template<int K, int O, int KSEG, int R>
__device__ __forceinline__ void gemm_rowsR(const float* xr, const float* W, const float* bias,
                                           float* yl, float* yg, int ygstride) {
  constexpr int KPT = K / KSEG;
  constexpr int OPP = 256 / KSEG;
  const int t = threadIdx.x;
  const int ks = t % KSEG;
  const int oi = t / KSEG;
#pragma unroll
  for (int pass = 0; pass < O / OPP; ++pass) {
    const int o = pass * OPP + oi;
    float a[R];
#pragma unroll
    for (int r = 0; r < R; ++r) a[r] = 0.0f;
    const float* wp = W + (size_t)o * K + ks * KPT;
    const float* xb = xr + ks * KPT;
#pragma unroll 4
    for (int kc = 0; kc < KPT; kc += 4) {
      f32x4 w4 = *(const f32x4*)(wp + kc);
#pragma unroll
      for (int r = 0; r < R; ++r) {
        f32x4 x = *(const f32x4*)(xb + r * K + kc);
#pragma unroll
        for (int j = 0; j < 4; ++j) a[r] += x[j] * w4[j];
      }
    }
#pragma unroll
    for (int d = 1; d < KSEG; d <<= 1)
#pragma unroll
      for (int r = 0; r < R; ++r) a[r] += __shfl_xor(a[r], d, 64);
    if (ks == 0) {
      float bv = bias ? bias[o] : 0.0f;
#pragma unroll
      for (int r = 0; r < R; ++r) {
        float v = a[r] + bv;
        if (yl) yl[r * O + o] = v;
        if (yg) yg[(size_t)r * ygstride + o] = v;
      }
    }
  }
}

// ---------------------------------------------------------------------------
// W1: fold weights. Mfull[hf][c]; vb[c][16] bf16 (h>=8 zero); cbe; sconst.
// ---------------------------------------------------------------------------
__global__ __launch_bounds__(256) void kW1(const float* We_w, const float* We_b, const float* attn,
                                           const float* We2_w, const float* We2_b,
                                           const float* edge_w, const float* edge_b,
                                           float* Mfull, u16* vb, float* cbe, float* sconst) {
  int gid = blockIdx.x * 256 + threadIdx.x;
  if (gid < 16384) {
    int hf = gid >> 7, c = gid & 127;
    int h = hf >> 4, fo = hf & 15;
    float s = 0;
    for (int e = 0; e < 16; ++e)
      s += edge_w[fo * 176 + e] * We2_w[(h * 16 + e) * 128 + c];
    Mfull[hf * 128 + c] = s;
  } else if (gid < 16384 + 2048) {
    int idx = gid - 16384;
    int c = idx >> 4, hc = idx & 15;
    float s = 0;
    if (hc < 8)
      for (int e = 0; e < 16; ++e)
        s += We_w[(hc * 16 + e) * 128 + c] * attn[128 + e];
    vb[c * 16 + hc] = f2b(s);
  } else if (gid < 18432 + 128) {
    int hf = gid - 18432;
    int h = hf >> 4, fo = hf & 15;
    float s = edge_b[fo];
    for (int e = 0; e < 16; ++e)
      s += We2_b[h * 16 + e] * edge_w[fo * 176 + e];
    cbe[hf] = s;
  } else if (gid < 18560 + 8) {
    int h = gid - 18560;
    float s = 0;
    for (int e = 0; e < 16; ++e)
      s += We_b[h * 16 + e] * attn[128 + e];
    sconst[h] = s;
  }
}

// W2: G[o][c] bf16
__global__ __launch_bounds__(256) void kW2(const float* oute_w, const float* Mfull, u16* Gb) {
  int gid = blockIdx.x * 256 + threadIdx.x;
  int o = gid >> 7, c = gid & 127;
  float s = 0;
  for (int k = 0; k < 128; ++k)
    s += oute_w[o * 128 + k] * Mfull[k * 128 + c];
  Gb[o * 128 + c] = f2b(s);
}

// ---------------------------------------------------------------------------
// N1: per 2 node-rows (grid 512): npj, dpj, node_wh, srow, scol
// ---------------------------------------------------------------------------
__global__ __launch_bounds__(256) void kN1(const float* node, const float* diff,
                                           const float* Wn_w, const float* Wn_b,
                                           const float* Wd_w, const float* Wd_b,
                                           const float* Wh_w, const float* Wh_b,
                                           const float* attn, const float* sconst,
                                           float* npj_g, float* nwh_g,
                                           float* srow_g, float* scol_g) {
  __shared__ float nrow[2 * 512], npjl[2 * 512], drow[2 * 128], dpjl[2 * 128];
  const int t = threadIdx.x;
  const int r0 = blockIdx.x * 2;
  *(f32x4*)&nrow[t * 4] = *(const f32x4*)(node + (size_t)r0 * 512 + t * 4);
  if (t < 64) *(f32x4*)&drow[t * 4] = *(const f32x4*)(diff + (size_t)r0 * 128 + t * 4);
  __syncthreads();
  gemm_rowsR<512, 512, 4, 2>(nrow, Wn_w, Wn_b, npjl, npj_g + (size_t)r0 * 512, 512);
  gemm_rowsR<128, 128, 4, 2>(drow, Wd_w, Wd_b, dpjl, nullptr, 0);
  __syncthreads();
  {
    int d = t & 63, hh = t >> 6;
#pragma unroll
    for (int hi = 0; hi < 2; ++hi) {
      int h = hh + hi * 4;
      float wb = Wh_b[d];
      float acc[2] = {wb, wb};
      for (int k = 0; k < 64; ++k) {
        float w = Wh_w[d * 64 + k];
#pragma unroll
        for (int r = 0; r < 2; ++r) acc[r] += npjl[r * 512 + h * 64 + k] * w;
      }
#pragma unroll
      for (int r = 0; r < 2; ++r) nwh_g[(size_t)(r0 + r) * 512 + h * 64 + d] = acc[r];
    }
  }
  if (t < 16) {
    int r = t >> 3, h = t & 7;
    float shi = 0, shj = 0, sdi = 0, sdj = 0;
    for (int d = 0; d < 64; ++d) {
      float x = npjl[r * 512 + h * 64 + d];
      shi += x * attn[d];
      shj += x * attn[64 + d];
    }
    for (int e = 0; e < 16; ++e) {
      float x = dpjl[r * 128 + h * 16 + e];
      sdi += x * attn[144 + e];
      sdj += x * attn[160 + e];
    }
    srow_g[(r0 + r) * 8 + h] = shi + sdi + sconst[h];
    scol_g[(r0 + r) * 8 + h] = shj + sdj;
  }
}

// ---------------------------------------------------------------------------
// A v5: per (b,l) block (grid 1024). Coalesced direct-MFMA scores with 2-chunk
// deep register prefetch (no LDS staging, no cache). Then softmax + P + invs.
// ---------------------------------------------------------------------------
__global__ __launch_bounds__(256) void kA(const float* edge, const float* srow, const float* scol,
                                          const u16* vb, u16* P, float* invs) {
  __shared__ float smx[512 * 9];
  __shared__ float red[256];
  __shared__ float mxh8[8];
  const int bl = blockIdx.x;
  const int b = bl >> 9, l = bl & 511;
  const int t = threadIdx.x;
  const int lane = t & 63, w = t >> 6;
  const int colL = lane & 15, kg = lane >> 4;
  const int h = t & 7, seg = t >> 3;
  const int rbase = w * 128;

  bf16x8 bfr[4];
#pragma unroll
  for (int ks = 0; ks < 4; ++ks) {
    u16x8 u;
#pragma unroll
    for (int j = 0; j < 8; ++j) u[j] = vb[(ks * 32 + kg * 8 + j) * 16 + colL];
    bfr[ks] = __builtin_bit_cast(bf16x8, u);
  }

  const float* eb = edge + (size_t)bl * 65536;

#define LOADC(BUF, CI)                                                       \
  {                                                                          \
    const float* rp = eb + (size_t)(rbase + (CI) * 16 + colL) * 128 + kg * 8;\
    _Pragma("unroll") for (int ks = 0; ks < 4; ++ks) {                       \
      BUF[2 * ks]     = *(const f32x4*)(rp + ks * 32);                       \
      BUF[2 * ks + 1] = *(const f32x4*)(rp + ks * 32 + 4);                   \
    }                                                                        \
  }
#define PROCC(BUF, CI)                                                       \
  {                                                                          \
    f32x4 acc = {0, 0, 0, 0};                                                \
    _Pragma("unroll") for (int ks = 0; ks < 4; ++ks) {                       \
      u16x8 a8;                                                              \
      _Pragma("unroll") for (int j = 0; j < 4; ++j) {                        \
        a8[j]     = f2b(BUF[2 * ks][j]);                                     \
        a8[4 + j] = f2b(BUF[2 * ks + 1][j]);                                 \
      }                                                                      \
      acc = __builtin_amdgcn_mfma_f32_16x16x32_bf16(                         \
          __builtin_bit_cast(bf16x8, a8), bfr[ks], acc, 0, 0, 0);            \
    }                                                                        \
    if (colL < 8) {                                                          \
      _Pragma("unroll") for (int r = 0; r < 4; ++r)                          \
        smx[(rbase + (CI) * 16 + kg * 4 + r) * 9 + colL] = acc[r];           \
    }                                                                        \
  }

  f32x4 A[8], B[8];
  LOADC(A, 0); LOADC(B, 1);
  PROCC(A, 0); LOADC(A, 2);
  PROCC(B, 1); LOADC(B, 3);
  PROCC(A, 2); LOADC(A, 4);
  PROCC(B, 3); LOADC(B, 5);
  PROCC(A, 4); LOADC(A, 6);
  PROCC(B, 5); LOADC(B, 7);
  PROCC(A, 6);
  PROCC(B, 7);
#undef LOADC
#undef PROCC
  __syncthreads();

  // softmax pass 1
  const float srh2 = srow[(size_t)bl * 8 + h];
  float mx = -__builtin_inff();
#pragma unroll 4
  for (int i = 0; i < 16; ++i) {
    int m = seg * 16 + i;
    float sv = smx[m * 9 + h] + srh2 + scol[((size_t)b * 512 + m) * 8 + h];
    sv = (m == l) ? -__builtin_inff() : (sv >= 0.0f ? sv : LRS * sv);
    smx[m * 9 + h] = sv;
    mx = fmaxf(mx, sv);
  }
  red[t] = mx;
  __syncthreads();
  if (t < 8) {
    float m2 = -__builtin_inff();
    for (int sg = 0; sg < 32; ++sg) m2 = fmaxf(m2, red[sg * 8 + t]);
    mxh8[t] = m2;
  }
  __syncthreads();
  float mh = mxh8[h];
  float smv = 0;
#pragma unroll 4
  for (int i = 0; i < 16; ++i) {
    int m = seg * 16 + i;
    float p = __expf(smx[m * 9 + h] - mh);
    smx[m * 9 + h] = p;
    smv += p;
  }
  red[t] = smv;
  __syncthreads();
  if (t < 8) {
    float s2 = 0;
    for (int sg = 0; sg < 32; ++sg) s2 += red[sg * 8 + t];
    invs[(size_t)bl * 8 + t] = 1.0f / s2;
  }
  __syncthreads();
  // write P bf16 [b][h][l][m]
#pragma unroll
  for (int k = 0; k < 2; ++k) {
    int c = k * 256 + t;
    int hp = c >> 6, mb = (c & 63) * 8;
    u16x8 pk;
#pragma unroll
    for (int j = 0; j < 8; ++j) pk[j] = f2b(smx[(mb + j) * 9 + hp]);
    *(u16x8*)(P + (((size_t)b * 8 + hp) * 512 + l) * 512 + mb) = pk;
  }
}

// ---------------------------------------------------------------------------
// Agg: per (b,h,ltile64): agg[l][d] = sum_m P[b,h,l,m]*nwh[b,m,h*64+d]
// ---------------------------------------------------------------------------
__global__ __launch_bounds__(256) void kAgg(const u16* P, const float* nwh, const float* npj,
                                            const float* invs, float* nnp) {
  __shared__ u16 Pt[8192];
  __shared__ u16 Vt[8192];
  const int bid = blockIdx.x;
  const int lt = bid & 7, h = (bid >> 3) & 7, b = bid >> 6;
  const int l0 = lt * 64;
  const int t = threadIdx.x;
  const int lane = t & 63, w = t >> 6;
  const int colL = lane & 15, kg = lane >> 4;

  f32x4 acc[4] = {};
  for (int mc = 0; mc < 4; ++mc) {
#pragma unroll
    for (int q = 0; q < 4; ++q) {
      int c = q * 256 + t;
      int row = c >> 4, cu = c & 15;
      u16x8 a8 = *(const u16x8*)(P + (((size_t)b * 8 + h) * 512 + l0 + row) * 512 + mc * 128 + cu * 8);
      *(u16x8*)(Pt + (row * 16 + (cu ^ (row & 7))) * 8) = a8;
    }
#pragma unroll
    for (int q = 0; q < 8; ++q) {
      int c = q * 256 + t;
      int m = c >> 4, d4 = (c & 15) * 4;
      f32x4 v = *(const f32x4*)(nwh + ((size_t)b * 512 + mc * 128 + m) * 512 + h * 64 + d4);
#pragma unroll
      for (int j = 0; j < 4; ++j) {
        int d = d4 + j;
        Vt[(d * 16 + ((m >> 3) ^ (d & 7))) * 8 + (m & 7)] = f2b(v[j]);
      }
    }
    __syncthreads();
#pragma unroll
    for (int kc = 0; kc < 4; ++kc) {
      int cu = kc * 4 + kg;
      int prow = w * 16 + colL;
      bf16x8 af = *(bf16x8*)(Pt + (prow * 16 + (cu ^ (prow & 7))) * 8);
#pragma unroll
      for (int n = 0; n < 4; ++n) {
        int d = n * 16 + colL;
        bf16x8 bf = *(bf16x8*)(Vt + (d * 16 + (cu ^ (d & 7))) * 8);
        acc[n] = __builtin_amdgcn_mfma_f32_16x16x32_bf16(af, bf, acc[n], 0, 0, 0);
      }
    }
    __syncthreads();
  }
#pragma unroll
  for (int r = 0; r < 4; ++r) {
    int l = l0 + w * 16 + kg * 4 + r;
    float iv = invs[((size_t)b * 512 + l) * 8 + h];
#pragma unroll
    for (int n = 0; n < 4; ++n) {
      int o = h * 64 + n * 16 + colL;
      size_t idx = ((size_t)b * 512 + l) * 512 + o;
      float a = acc[n][r] * iv;
      a = a >= 0.0f ? a : LRS * a;
      nnp[idx] = npj[idx] + a;
    }
  }
}

// ---------------------------------------------------------------------------
// N234 (fused, 2 rows/block, grid 512): nnp -> out0 -> np2/dp2 -> R -> Pl/Pm
// ---------------------------------------------------------------------------
__global__ __launch_bounds__(256) void kN234(const float* nnp, const float* diff,
                                             const float* outn_w, const float* outn_b,
                                             const float* Wn2_w, const float* Wn2_b,
                                             const float* Wd2_w, const float* Wd2_b,
                                             const float* edge_w, const float* cbe,
                                             const float* oute_w, const float* oute_b,
                                             float* out0, float* Pl, float* Pm) {
  __shared__ float xr[2 * 512], o0l[2 * 512], np2l[2 * 512], dr[2 * 128], dp2l[2 * 128];
  __shared__ float Rls[2 * 128], Rms[2 * 128];
  const int t = threadIdx.x;
  const int r0 = blockIdx.x * 2;
  *(f32x4*)&xr[t * 4] = *(const f32x4*)(nnp + (size_t)r0 * 512 + t * 4);
  if (t < 64) *(f32x4*)&dr[t * 4] = *(const f32x4*)(diff + (size_t)r0 * 128 + t * 4);
  __syncthreads();
  gemm_rowsR<512, 512, 4, 2>(xr, outn_w, outn_b, o0l, out0 + (size_t)r0 * 512, 512);
  gemm_rowsR<128, 128, 4, 2>(dr, Wd2_w, Wd2_b, dp2l, nullptr, 0);
  __syncthreads();
  gemm_rowsR<512, 512, 4, 2>(o0l, Wn2_w, Wn2_b, np2l, nullptr, 0);
  __syncthreads();
  {
    int hf = t & 127, which = t >> 7;
    int h = hf >> 4, fo = hf & 15;
    const float* wh = edge_w + fo * 176 + 16 + which * 64;
    const float* wd = edge_w + fo * 176 + 144 + which * 16;
    float add = which ? 0.0f : cbe[hf];
    float* dst = which ? Rms : Rls;
#pragma unroll
    for (int r = 0; r < 2; ++r) {
      float a = add;
      for (int d = 0; d < 64; ++d) a += np2l[r * 512 + h * 64 + d] * wh[d];
      for (int e = 0; e < 16; ++e) a += dp2l[r * 128 + h * 16 + e] * wd[e];
      dst[r * 128 + hf] = a;
    }
  }
  __syncthreads();
  gemm_rowsR<128, 128, 4, 2>(Rls, oute_w, oute_b, nullptr, Pl + (size_t)r0 * 128, 128);
  gemm_rowsR<128, 128, 4, 2>(Rms, oute_w, nullptr, nullptr, Pm + (size_t)r0 * 128, 128);
}

// ---------------------------------------------------------------------------
// E: direct-f32, grid 8192 (64-row tile). Lane-contiguous staging loads
// (lane t at byte t*16 + k*4096), bf16 convert, swizzled LDS; G in VGPRs;
// one barrier.
// ---------------------------------------------------------------------------
__global__ __launch_bounds__(256) void kE(const float* edge, const u16* Gb,
                                          const float* Pl, const float* Pm, float* oute) {
  __shared__ u16 At[8192];
  const int tile = blockIdx.x;
  const int bl = tile >> 3;
  const int b = bl >> 9;
  const int r0 = (tile & 7) * 64;
  const int t = threadIdx.x, lane = t & 63, w = t >> 6;
  const int colL = lane & 15, kg = lane >> 4;

  bf16x8 gf[2][4];
#pragma unroll
  for (int n = 0; n < 2; ++n)
#pragma unroll
    for (int ks = 0; ks < 4; ++ks) {
      int o = w * 32 + n * 16 + colL;
      gf[n][ks] = *(const bf16x8*)(Gb + o * 128 + ks * 32 + kg * 8);
    }
  f32x4 plv4[2];
#pragma unroll
  for (int n = 0; n < 2; ++n)
    plv4[n] = *(const f32x4*)(Pl + (size_t)bl * 128 + w * 32 + n * 16 + kg * 4);

  // stage: 64x128 f32 tile -> bf16 swizzled LDS, lane-contiguous reads
  const float* src = edge + ((size_t)bl * 512 + r0) * 128;
#pragma unroll
  for (int k = 0; k < 8; ++k) {
    int fidx = t * 4 + k * 1024;
    f32x4 v = *(const f32x4*)(src + fidx);
    int row = fidx >> 7, col = fidx & 127;
    int cu = col >> 3, sub = col & 7;   // sub in {0,4}
    u16x4 pk;
#pragma unroll
    for (int j = 0; j < 4; ++j) pk[j] = f2b(v[j]);
    *(u16x4*)(At + (row * 16 + (cu ^ (row & 7))) * 8 + sub) = pk;
  }
  __syncthreads();

  f32x4 acc[4][2] = {};
#pragma unroll
  for (int i = 0; i < 4; ++i) {
#pragma unroll
    for (int ks = 0; ks < 4; ++ks) {
      int cu = ks * 4 + kg;
      int row = i * 16 + colL;
      bf16x8 af = *(bf16x8*)(At + (row * 16 + (cu ^ (row & 7))) * 8);
#pragma unroll
      for (int n = 0; n < 2; ++n)
        acc[i][n] = __builtin_amdgcn_mfma_f32_16x16x32_bf16(gf[n][ks], af, acc[i][n], 0, 0, 0);
    }
  }
  float* ob = oute + ((size_t)bl * 512 + r0) * 128;
#pragma unroll
  for (int i = 0; i < 4; ++i) {
    int m = i * 16 + colL;
    const float* pmp = Pm + ((size_t)b * 512 + r0 + m) * 128;
    float* orow = ob + (size_t)m * 128;
#pragma unroll
    for (int n = 0; n < 2; ++n) {
      int oc = w * 32 + n * 16 + kg * 4;
      f32x4 pm4 = *(const f32x4*)(pmp + oc);
      f32x4 o4;
#pragma unroll
      for (int r = 0; r < 4; ++r) o4[r] = acc[i][n][r] + plv4[n][r] + pm4[r];
      *(f32x4*)(orow + oc) = o4;
    }
  }
}

extern "C" void kernel_launch(void* const* d_in, const int* in_sizes, int n_in,
                              void* d_out, int out_size, void* d_ws, size_t ws_size,
                              hipStream_t stream) {
  (void)in_sizes; (void)n_in; (void)out_size; (void)ws_size;
  const float* node   = (const float*)d_in[0];
  const float* edge   = (const float*)d_in[1];
  const float* diff   = (const float*)d_in[2];
  const float* Wn_w   = (const float*)d_in[3];
  const float* Wn_b   = (const float*)d_in[4];
  const float* We_w   = (const float*)d_in[5];
  const float* We_b   = (const float*)d_in[6];
  const float* Wd_w   = (const float*)d_in[7];
  const float* Wd_b   = (const float*)d_in[8];
  const float* Wh_w   = (const float*)d_in[9];
  const float* Wh_b   = (const float*)d_in[10];
  const float* attn   = (const float*)d_in[11];
  const float* outn_w = (const float*)d_in[12];
  const float* outn_b = (const float*)d_in[13];
  const float* Wn2_w  = (const float*)d_in[14];
  const float* Wn2_b  = (const float*)d_in[15];
  const float* We2_w  = (const float*)d_in[16];
  const float* We2_b  = (const float*)d_in[17];
  const float* Wd2_w  = (const float*)d_in[18];
  const float* Wd2_b  = (const float*)d_in[19];
  const float* edge_w = (const float*)d_in[20];
  const float* edge_b = (const float*)d_in[21];
  const float* oute_w = (const float*)d_in[22];
  const float* oute_b = (const float*)d_in[23];

  float* out0 = (float*)d_out;
  float* out1 = out0 + 524288;

  float* f = (float*)d_ws;
  size_t off = 0;
  auto alloc = [&](size_t n) { float* p = f + off; off += (n + 7) & ~(size_t)7; return p; };
  float* npj    = alloc(524288);
  float* nwh    = alloc(524288);
  float* srow   = alloc(8192);
  float* scol   = alloc(8192);
  float* sconst = alloc(8);
  float* cbe    = alloc(128);
  float* Mfull  = alloc(16384);
  float* nnp    = alloc(524288);
  float* Pl     = alloc(131072);
  float* Pm     = alloc(131072);
  float* invs   = alloc(8192);
  u16* vb = (u16*)(f + off); off += 1024;
  u16* Gb = (u16*)(f + off); off += 8192;
  u16* P  = (u16*)(f + off); off += 2097152;

  hipLaunchKernelGGL(kW1, dim3(73), dim3(256), 0, stream,
                     We_w, We_b, attn, We2_w, We2_b, edge_w, edge_b, Mfull, vb, cbe, sconst);
  hipLaunchKernelGGL(kW2, dim3(64), dim3(256), 0, stream, oute_w, Mfull, Gb);
  hipLaunchKernelGGL(kN1, dim3(512), dim3(256), 0, stream,
                     node, diff, Wn_w, Wn_b, Wd_w, Wd_b, Wh_w, Wh_b, attn, sconst,
                     npj, nwh, srow, scol);
  hipLaunchKernelGGL(kA, dim3(1024), dim3(256), 0, stream,
                     edge, srow, scol, vb, P, invs);
  hipLaunchKernelGGL(kAgg, dim3(128), dim3(256), 0, stream, P, nwh, npj, invs, nnp);
  hipLaunchKernelGGL(kN234, dim3(512), dim3(256), 0, stream,
                     nnp, diff, outn_w, outn_b, Wn2_w, Wn2_b, Wd2_w, Wd2_b,
                     edge_w, cbe, oute_w, oute_b, out0, Pl, Pm);
  hipLaunchKernelGGL(kE, dim3(8192), dim3(256), 0, stream, edge, Gb, Pl, Pm, out1);
}